// Round 13
// baseline (179.810 us; speedup 1.0000x reference)
//
#include <hip/hip_runtime.h>
#include <hip/hip_bf16.h>

#define B_ 512
#define S_ 256
#define N_ 180
#define BS_ (B_*S_)            // 131072
#define BSN_ ((long)BS_*N_)    // 23592960
#define CPN_ ((long)B_*16*N_)  // checkpoint elems
#define A16F 0.028147497671065603f   // 0.8^16

typedef __attribute__((ext_vector_type(4))) float f32x4;
typedef __attribute__((ext_vector_type(4))) short s16x4;
typedef __attribute__((ext_vector_type(8))) short s16x8;

static __device__ inline short f2bf(float f) {
  union { float f; unsigned u; } v; v.f = f;
  unsigned r = v.u + 0x7FFF + ((v.u >> 16) & 1);   // RNE
  return (short)(r >> 16);
}
static __device__ inline float bf2f(short h) {
  union { float f; unsigned u; } v; v.u = ((unsigned)(unsigned short)h) << 16;
  return v.f;
}
static __device__ inline f32x4 bf4_to_f4(s16x4 h) {
  f32x4 v; v.x = bf2f(h.x); v.y = bf2f(h.y); v.z = bf2f(h.z); v.w = bf2f(h.w);
  return v;
}
static __device__ inline void lds_barrier() {
  asm volatile("s_waitcnt lgkmcnt(0)" ::: "memory");
  __builtin_amdgcn_s_barrier();
}

// K_aux: grid (17, B_).
//  x < 16 : k_a work for (chunk x, batch b): u16t (transposed bf16 u) + P + prec
//  x == 16: k_cp (l4/adapt checkpoints for batch b) + k0 fold (cfrag, b<144)
__global__ __launch_bounds__(256) void k_aux(
    const float* __restrict__ logits, const float* __restrict__ plog,
    const int* __restrict__ ori, const float* __restrict__ narrow,
    const float* __restrict__ broad,
    float* __restrict__ prec, float* __restrict__ P,
    short* __restrict__ u16t, float* __restrict__ cp_a,
    float* __restrict__ cp_l4, short* __restrict__ cfrag) {
  int x = blockIdx.x, b = blockIdx.y;
  int tid = threadIdx.x;

  if (x == 16) {
    // ---- k_cp: serial l4/adapt checkpoint scan (reads only ori) ----
    __shared__ int o_l[256];
    o_l[tid] = ori[b*S_ + tid];
    __syncthreads();
    if (tid < N_) {
      int n = tid;
      float a = 0.f, l4 = 0.f;
      long cb = (long)b * 16 * N_ + n;
      for (int s = 0; s < S_; ++s) {
        if ((s & 15) == 0) {
          cp_a [cb + (s >> 4) * N_] = a;
          cp_l4[cb + (s >> 4) * N_] = l4;
        }
        a = 0.9f * a + 0.2f * l4;
        if (n == o_l[s]) {
          float d = fmaxf(1.f - a, 0.f);
          l4 = d * __builtin_amdgcn_rcpf(1.f + d * (1.f/180.f));
        } else l4 = 0.f;
      }
    }
    // ---- k0 fold: cfrag built by blocks b < 144 ----
    if (b < 144) {
      int idx = b * 256 + tid;
      if (idx < 12*6*64*8) {
        int j    = idx & 7;
        int lane = (idx >> 3) & 63;
        int g    = idx >> 9;
        int ks   = g % 6;
        int nt   = g / 6;
        int k = ks*32 + (lane >> 4)*8 + j;
        int c = nt*16 + (lane & 15);
        float v = 0.f;
        if (k < N_ && c < N_) v = broad[k*N_ + c] - 0.5f*narrow[k*N_ + c];
        cfrag[idx] = f2bf(v);
      }
    }
    return;
  }

  // ---- k_a: chunk x, batch b ----
  __shared__ float u[16*180];
  int k = x;
  int w = tid >> 6, l = tid & 63;
  bool seg2 = (l < N_ - 128);
  int s0 = k * 16;
  const float* Lb = logits + ((long)b*S_ + s0) * N_;
  #pragma unroll
  for (int q = 0; q < 4; ++q) {
    int r = w*4 + q;
    const float* rp = Lb + (long)r * N_;
    float e0 = __expf(rp[l]);
    float e1 = __expf(rp[l + 64]);
    float e2 = seg2 ? __expf(rp[l + 128]) : 0.f;
    float s = e0 + e1 + e2;
    #pragma unroll
    for (int o = 32; o; o >>= 1) s += __shfl_xor(s, o);
    float pr = 1.f / (1.f + __expf(-plog[b*S_ + s0 + r]));
    float scv = 0.2f * pr / s;
    if (l == 0) prec[b*S_ + s0 + r] = pr;
    u[r*180 + l] = e0 * scv;
    u[r*180 + l + 64] = e1 * scv;
    if (seg2) u[r*180 + l + 128] = e2 * scv;
  }
  __syncthreads();
  if (tid < N_) {
    int n = tid;
    // transposed u16t: [b][k][n][16] — thread writes 32 contiguous bytes
    s16x8 h0, h1;
    #pragma unroll
    for (int r = 0; r < 8; ++r) h0[r] = f2bf(u[r*180 + n]);
    #pragma unroll
    for (int r = 0; r < 8; ++r) h1[r] = f2bf(u[(r + 8)*180 + n]);
    short* ub = u16t + ((long)(b*16 + k) * N_ + n) * 16;
    *(s16x8*)ub = h0;
    *(s16x8*)(ub + 8) = h1;
    // chunk-local template partial (Horner)
    float c = 0.f;
    #pragma unroll
    for (int r = 0; r < 16; ++r) c = 0.8f * c + u[r*180 + n];
    P[((long)b*16 + k) * N_ + n] = c;
  }
}

// K_main: grid (16, B_) — one block per (chunk c, batch b). Computes its own
// template boundary (Horner over P), W=c?16:0 warm rows from exact
// checkpoints, l23 via 0.5-contraction. bf16 LDS staging; wave 3 streams
// template+comparator NT stores during the scan phase.
__global__ __launch_bounds__(256, 3) void k_main(
    const int* __restrict__ ori, const short* __restrict__ u16t,
    const float* __restrict__ prec, const float* __restrict__ P,
    const float* __restrict__ cp_a, const float* __restrict__ cp_l4,
    const short* __restrict__ cfrag, float* __restrict__ out) {
  __shared__ short At[32 * 200];      // template bf16, padded K (stride 200)
  __shared__ short cmpb[32 * 180];    // comparator bf16
  __shared__ short stg[3][16 * 180];  // l4 / l23 / adapt, bf16
  __shared__ float pr_l[32];
  __shared__ int o_l[32];

  int c = blockIdx.x;
  int b = blockIdx.y;
  int W = c ? 16 : 0;
  int nrow = W + 16;
  int s0 = c * 16 - W;
  int tid = threadIdx.x, w = tid >> 6, l = tid & 63, lr = l & 15, lg = l >> 4;
  bool act = (tid < N_);
  int n = tid;

  if (tid < nrow) {
    int s = s0 + tid;
    pr_l[tid] = prec[b*S_ + s];
    o_l[tid]  = ori[b*S_ + s];
  }
  for (int i = tid; i < 32 * 20; i += 256) {   // zero-pad At cols 180..199
    int r = i / 20, q = i - r * 20;
    At[r * 200 + 180 + q] = 0;
  }
  long bnd = c ? (((long)b*16 + (c - 1)) * N_ + n) : 0;
  float* base = out + ((long)b*S_ + c*16) * N_;

  // ---- phase 0+1: template boundary via Horner over P, then recursion ----
  if (act) {
    float t = 0.f;
    if (c) {
      long pb = (long)b * 16 * N_ + n;
      for (int k = 0; k < c - 1; ++k)
        t = A16F * t + P[pb + k * N_];   // prefix up to chunk c-2 = state at (c-1)*16
    }
    // warm rows (chunk c-1) + real rows (chunk c), dense transposed reads
    const short* ub = u16t + ((long)(b*16 + c) * N_ + n) * 16;
    if (c) {
      const short* uw = u16t + ((long)(b*16 + c - 1) * N_ + n) * 16;
      s16x8 h0 = *(const s16x8*)uw;
      s16x8 h1 = *(const s16x8*)(uw + 8);
      #pragma unroll
      for (int r = 0; r < 8; ++r) {
        t = 0.8f * t + bf2f(h0[r]);
        At[r * 200 + n] = f2bf(t);
      }
      #pragma unroll
      for (int r = 0; r < 8; ++r) {
        t = 0.8f * t + bf2f(h1[r]);
        At[(8 + r) * 200 + n] = f2bf(t);
      }
    }
    {
      s16x8 h0 = *(const s16x8*)ub;
      s16x8 h1 = *(const s16x8*)(ub + 8);
      #pragma unroll
      for (int r = 0; r < 8; ++r) {
        t = 0.8f * t + bf2f(h0[r]);
        At[(W + r) * 200 + n] = f2bf(t);
      }
      #pragma unroll
      for (int r = 0; r < 8; ++r) {
        t = 0.8f * t + bf2f(h1[r]);
        At[(W + 8 + r) * 200 + n] = f2bf(t);
      }
    }
  }
  lds_barrier();

  // ---- phase 2: comparator GEMM (template @ C) * prec -> cmpb (bf16) ----
  {
    int mts = c ? 2 : 1;
    for (int i = 0; i < 3; ++i) {
      int ntile = i * 4 + w;
      s16x8 bfv[6];
      #pragma unroll
      for (int ks = 0; ks < 6; ++ks)
        bfv[ks] = *(const s16x8*)(cfrag + ((ntile*6 + ks)*64 + l)*8);
      for (int mt = 0; mt < mts; ++mt) {
        f32x4 acc = (f32x4)(0.f);
        #pragma unroll
        for (int ks = 0; ks < 6; ++ks) {
          s16x8 af = *(const s16x8*)(&At[(mt*16 + lr)*200 + ks*32 + lg*8]);
          acc = __builtin_amdgcn_mfma_f32_16x16x32_bf16(af, bfv[ks], acc, 0, 0, 0);
        }
        int col = ntile * 16 + lr;
        if (col < N_) {
          #pragma unroll
          for (int r = 0; r < 4; ++r) {
            int row = mt*16 + lg*4 + r;
            cmpb[row * 180 + col] = f2bf(acc[r] * pr_l[row]);
          }
        }
      }
    }
  }
  lds_barrier();

  // ---- phase 3 (threads 0..179): l4/adapt/l23 -> stg (bf16)
  // ---- phase 4a (wave 3): stream template+comparator NT stores meanwhile
  if (act) {
    float a  = c ? cp_a [bnd] : 0.f;
    float l4 = c ? cp_l4[bnd] : 0.f;
    float cl = 0.f;
    for (int jc = 0; jc < nrow; jc += 8) {
      float tv[8], qv[8]; int ov[8];
      #pragma unroll
      for (int r = 0; r < 8; ++r) {
        tv[r] = bf2f(At[(jc + r) * 200 + n]);
        qv[r] = bf2f(cmpb[(jc + r) * 180 + n]);
        ov[r] = o_l[jc + r];
      }
      #pragma unroll
      for (int r = 0; r < 8; ++r) {
        int j = jc + r;
        a = 0.9f * a + 0.2f * l4;
        float d = (n == ov[r]) ? fmaxf(1.f - a, 0.f) : 0.f;
        l4 = d * __builtin_amdgcn_rcpf(1.f + d * (1.f/180.f));
        cl = fmaxf(l4 + 0.5f * cl + tv[r] - qv[r], 0.f);
        if (j >= W) {
          int jj = j - W;
          stg[0][jj*180 + n] = f2bf(l4);
          stg[1][jj*180 + n] = f2bf(cl);
          stg[2][jj*180 + n] = f2bf(a);
        }
      }
    }
  } else if (tid >= 192) {
    // wave 3: 1440 groups (2 streams x 16 rows x 45 f32x4)
    for (int g = tid - 192; g < 1440; g += 64) {
      int st = g / 720;
      int i  = g - st * 720;
      int j = i / 45, c4 = i - j * 45;
      long ro = (long)j * N_ + c4 * 4;
      if (st == 0) {
        s16x4 h = *(const s16x4*)&At[(W + j)*200 + c4*4];
        __builtin_nontemporal_store(bf4_to_f4(h), (f32x4*)(base + 2*BSN_ + ro));
      } else {
        s16x4 h = *(const s16x4*)&cmpb[(W + j)*180 + c4*4];
        __builtin_nontemporal_store(bf4_to_f4(h), (f32x4*)(base + 4*BSN_ + ro));
      }
    }
  }
  lds_barrier();

  // ---- phase 4b: l4/l23/adapt NT stores (slots 0, 1, 3) ----
  for (int i = tid; i < 2160; i += 256) {
    int st = i / 720;
    int r  = i - st * 720;
    int j = r / 45, c4 = r - j * 45;
    long ro = (long)j * N_ + c4 * 4;
    long slot = (st == 2) ? 3 : st;     // l4->0, l23->1, adapt->3
    s16x4 h = *(const s16x4*)&stg[st][j*180 + c4*4];
    __builtin_nontemporal_store(bf4_to_f4(h), (f32x4*)(base + slot*BSN_ + ro));
  }
}

extern "C" void kernel_launch(void* const* d_in, const int* in_sizes, int n_in,
                              void* d_out, int out_size, void* d_ws, size_t ws_size,
                              hipStream_t stream) {
  const int*   ori    = (const int*)d_in[0];
  const float* logits = (const float*)d_in[1];
  const float* plog   = (const float*)d_in[2];
  const float* narrow = (const float*)d_in[3];
  const float* broad  = (const float*)d_in[4];
  float* out = (float*)d_out;

  float* ws    = (float*)d_ws;
  float* prec  = ws;                  // BS_
  float* P     = ws + BS_;            // CPN_
  float* cp_a  = P + CPN_;            // CPN_
  float* cp_l4 = cp_a + CPN_;         // CPN_
  short* u16t  = (short*)(cp_l4 + CPN_);       // BSN_ shorts (47 MB), [b][c][n][16]
  short* cfrag = u16t + BSN_;                  // 36864 shorts

  k_aux<<<dim3(17, B_), 256, 0, stream>>>(logits, plog, ori, narrow, broad,
                                          prec, P, u16t, cp_a, cp_l4, cfrag);
  k_main<<<dim3(16, B_), 256, 0, stream>>>(ori, u16t, prec, P, cp_a, cp_l4,
                                           cfrag, out);
}

// Round 14
// 168.556 us; speedup vs baseline: 1.0668x; 1.0668x over previous
//
#include <hip/hip_runtime.h>
#include <hip/hip_bf16.h>

#define B_ 512
#define S_ 256
#define N_ 180
#define BS_ (B_*S_)            // 131072
#define BSN_ ((long)BS_*N_)    // 23592960
#define CPN_ ((long)B_*16*N_)  // checkpoint elems
#define A16F 0.028147497671065603f   // 0.8^16

typedef __attribute__((ext_vector_type(4))) float f32x4;
typedef __attribute__((ext_vector_type(4))) short s16x4;
typedef __attribute__((ext_vector_type(8))) short s16x8;

static __device__ inline short f2bf(float f) {
  union { float f; unsigned u; } v; v.f = f;
  unsigned r = v.u + 0x7FFF + ((v.u >> 16) & 1);   // RNE
  return (short)(r >> 16);
}
static __device__ inline float bf2f(short h) {
  union { float f; unsigned u; } v; v.u = ((unsigned)(unsigned short)h) << 16;
  return v.f;
}
static __device__ inline f32x4 bf4_to_f4(s16x4 h) {
  f32x4 v; v.x = bf2f(h.x); v.y = bf2f(h.y); v.z = bf2f(h.z); v.w = bf2f(h.w);
  return v;
}
static __device__ inline void lds_barrier() {
  asm volatile("s_waitcnt lgkmcnt(0)" ::: "memory");
  __builtin_amdgcn_s_barrier();
}

// K0: cfrag = MFMA B-fragments of C = broad - 0.5*narrow (bf16)
__global__ void k0_prep(const float* __restrict__ narrow, const float* __restrict__ broad,
                        short* __restrict__ cfrag) {
  int idx = blockIdx.x * 256 + threadIdx.x;
  if (idx >= 12*6*64*8) return;
  int j    = idx & 7;
  int lane = (idx >> 3) & 63;
  int g    = idx >> 9;
  int ks   = g % 6;
  int nt   = g / 6;
  int k = ks*32 + (lane >> 4)*8 + j;
  int c = nt*16 + (lane & 15);
  float v = 0.f;
  if (k < N_ && c < N_) v = broad[k*N_ + c] - 0.5f*narrow[k*N_ + c];
  cfrag[idx] = f2bf(v);
}

// K_cp: l4/adaptation boundary checkpoints (slots k=0..15), reads ONLY ori.
__global__ __launch_bounds__(256) void k_cp(const int* __restrict__ ori,
                                            float* __restrict__ cp_a,
                                            float* __restrict__ cp_l4) {
  __shared__ int o_l[256];
  int b = blockIdx.x, tid = threadIdx.x;
  o_l[tid] = ori[b*S_ + tid];
  __syncthreads();
  if (tid >= N_) return;
  int n = tid;
  float a = 0.f, l4 = 0.f;
  long cb = (long)b * 16 * N_ + n;
  for (int s = 0; s < S_; ++s) {
    if ((s & 15) == 0) {
      cp_a [cb + (s >> 4) * N_] = a;
      cp_l4[cb + (s >> 4) * N_] = l4;
    }
    a = 0.9f * a + 0.2f * l4;
    if (n == o_l[s]) {
      float d = fmaxf(1.f - a, 0.f);
      l4 = d * __builtin_amdgcn_rcpf(1.f + d * (1.f/180.f));
    } else l4 = 0.f;
  }
}

// K_a: one block per (chunk k, batch b). Single cold logits read: row sums ->
// scale/prec; chunk-local template partial P = Horner(0.8, u rows).
__global__ __launch_bounds__(256) void k_a(const float* __restrict__ logits,
                                           const float* __restrict__ plog,
                                           float* __restrict__ scale,
                                           float* __restrict__ prec,
                                           float* __restrict__ P) {
  __shared__ float u[16*180];
  int k = blockIdx.x, b = blockIdx.y;
  int tid = threadIdx.x, w = tid >> 6, l = tid & 63;
  bool seg2 = (l < N_ - 128);
  int s0 = k * 16;
  const float* Lb = logits + ((long)b*S_ + s0) * N_;
  #pragma unroll
  for (int q = 0; q < 4; ++q) {
    int r = w*4 + q;
    const float* rp = Lb + (long)r * N_;
    float e0 = __expf(rp[l]);
    float e1 = __expf(rp[l + 64]);
    float e2 = seg2 ? __expf(rp[l + 128]) : 0.f;
    float s = e0 + e1 + e2;
    #pragma unroll
    for (int o = 32; o; o >>= 1) s += __shfl_xor(s, o);
    float pr = 1.f / (1.f + __expf(-plog[b*S_ + s0 + r]));
    float scv = 0.2f * pr / s;
    if (l == 0) { scale[b*S_ + s0 + r] = scv; prec[b*S_ + s0 + r] = pr; }
    u[r*180 + l] = e0 * scv;
    u[r*180 + l + 64] = e1 * scv;
    if (seg2) u[r*180 + l + 128] = e2 * scv;
  }
  __syncthreads();
  if (tid < N_) {
    float c = 0.f;
    #pragma unroll
    for (int r = 0; r < 16; ++r) c = 0.8f * c + u[r*180 + tid];
    P[((long)b*16 + k) * N_ + tid] = c;
  }
}

// K_comb: cross-chunk template prefix: t_bnd[k] = 0.8^16 * t_bnd[k-1] + P[k-1]
__global__ void k_comb(const float* __restrict__ P, float* __restrict__ tbnd) {
  int t = blockIdx.x * 256 + threadIdx.x;   // exactly 92160 = 512*180
  int b = t / N_, n = t - b * N_;
  long pb = (long)b * 16 * N_ + n;
  float c = 0.f;
  tbnd[pb] = 0.f;
  #pragma unroll
  for (int k = 1; k < 16; ++k) {
    c = A16F * c + P[pb + (k - 1) * N_];
    tbnd[pb + k * N_] = c;
  }
}

// K_main: grid (16, B_) — one block per (chunk c, batch b). W = c?16:0 warm
// rows recomputed from exact boundary state (template/l4/adapt); l23 via
// 0.5-contraction warm-up. bf16 LDS staging (~42 KB -> 3 blk/CU); wave 3
// streams template+comparator NT stores during the scan phase.
__global__ __launch_bounds__(256, 3) void k_main(
    const int* __restrict__ ori, const float* __restrict__ logits,
    const float* __restrict__ scale, const float* __restrict__ prec,
    const float* __restrict__ cp_a, const float* __restrict__ cp_l4,
    const float* __restrict__ tbnd, const short* __restrict__ cfrag,
    float* __restrict__ out) {
  __shared__ short At[32 * 200];      // template bf16, padded K (stride 200)
  __shared__ short cmpb[32 * 180];    // comparator bf16
  __shared__ short stg[3][16 * 180];  // l4 / l23 / adapt, bf16
  __shared__ float sc_l[32], pr_l[32];
  __shared__ int o_l[32];

  int c = blockIdx.x;
  int b = blockIdx.y;
  int W = c ? 16 : 0;
  int nrow = W + 16;
  int s0 = c * 16 - W;
  int tid = threadIdx.x, w = tid >> 6, l = tid & 63, lr = l & 15, lg = l >> 4;
  bool act = (tid < N_);
  int n = tid;

  if (tid < nrow) {
    int s = s0 + tid;
    sc_l[tid] = scale[b*S_ + s];
    pr_l[tid] = prec[b*S_ + s];
    o_l[tid]  = ori[b*S_ + s];
  }
  for (int i = tid; i < 32 * 20; i += 256) {   // zero-pad At cols 180..199
    int r = i / 20, q = i - r * 20;
    At[r * 200 + 180 + q] = 0;
  }
  long bnd = c ? (((long)b*16 + (c - 1)) * N_ + n) : 0;
  float* base = out + ((long)b*S_ + c*16) * N_;
  lds_barrier();

  // ---- phase 1: template recursion from exact boundary (f32 logits) ----
  if (act) {
    float t = c ? tbnd[bnd] : 0.f;
    const float* lp = logits + ((long)b*S_ + s0) * N_ + n;
    for (int jc = 0; jc < nrow; jc += 8) {
      float xs[8];
      #pragma unroll
      for (int r = 0; r < 8; ++r) xs[r] = lp[(long)(jc + r) * N_];
      #pragma unroll
      for (int r = 0; r < 8; ++r) {
        t = 0.8f * t + __expf(xs[r]) * sc_l[jc + r];
        At[(jc + r) * 200 + n] = f2bf(t);
      }
    }
  }
  lds_barrier();

  // ---- phase 2: comparator GEMM (template @ C) * prec -> cmpb (bf16) ----
  {
    int mts = c ? 2 : 1;
    for (int i = 0; i < 3; ++i) {
      int ntile = i * 4 + w;
      s16x8 bfv[6];
      #pragma unroll
      for (int ks = 0; ks < 6; ++ks)
        bfv[ks] = *(const s16x8*)(cfrag + ((ntile*6 + ks)*64 + l)*8);
      for (int mt = 0; mt < mts; ++mt) {
        f32x4 acc = (f32x4)(0.f);
        #pragma unroll
        for (int ks = 0; ks < 6; ++ks) {
          s16x8 af = *(const s16x8*)(&At[(mt*16 + lr)*200 + ks*32 + lg*8]);
          acc = __builtin_amdgcn_mfma_f32_16x16x32_bf16(af, bfv[ks], acc, 0, 0, 0);
        }
        int col = ntile * 16 + lr;
        if (col < N_) {
          #pragma unroll
          for (int r = 0; r < 4; ++r) {
            int row = mt*16 + lg*4 + r;
            cmpb[row * 180 + col] = f2bf(acc[r] * pr_l[row]);
          }
        }
      }
    }
  }
  lds_barrier();

  // ---- phase 3 (threads 0..179): l4/adapt/l23 -> stg (bf16)
  // ---- phase 4a (wave 3): stream template+comparator NT stores meanwhile
  if (act) {
    float a  = c ? cp_a [bnd] : 0.f;
    float l4 = c ? cp_l4[bnd] : 0.f;
    float cl = 0.f;
    for (int jc = 0; jc < nrow; jc += 8) {
      float tv[8], qv[8]; int ov[8];
      #pragma unroll
      for (int r = 0; r < 8; ++r) {
        tv[r] = bf2f(At[(jc + r) * 200 + n]);
        qv[r] = bf2f(cmpb[(jc + r) * 180 + n]);
        ov[r] = o_l[jc + r];
      }
      #pragma unroll
      for (int r = 0; r < 8; ++r) {
        int j = jc + r;
        a = 0.9f * a + 0.2f * l4;
        float d = (n == ov[r]) ? fmaxf(1.f - a, 0.f) : 0.f;
        l4 = d * __builtin_amdgcn_rcpf(1.f + d * (1.f/180.f));
        cl = fmaxf(l4 + 0.5f * cl + tv[r] - qv[r], 0.f);
        if (j >= W) {
          int jj = j - W;
          stg[0][jj*180 + n] = f2bf(l4);
          stg[1][jj*180 + n] = f2bf(cl);
          stg[2][jj*180 + n] = f2bf(a);
        }
      }
    }
  } else if (tid >= 192) {
    // wave 3: 1440 groups (2 streams x 16 rows x 45 f32x4)
    for (int g = tid - 192; g < 1440; g += 64) {
      int st = g / 720;
      int i  = g - st * 720;
      int j = i / 45, c4 = i - j * 45;
      long ro = (long)j * N_ + c4 * 4;
      if (st == 0) {
        s16x4 h = *(const s16x4*)&At[(W + j)*200 + c4*4];
        __builtin_nontemporal_store(bf4_to_f4(h), (f32x4*)(base + 2*BSN_ + ro));
      } else {
        s16x4 h = *(const s16x4*)&cmpb[(W + j)*180 + c4*4];
        __builtin_nontemporal_store(bf4_to_f4(h), (f32x4*)(base + 4*BSN_ + ro));
      }
    }
  }
  lds_barrier();

  // ---- phase 4b: l4/l23/adapt NT stores (slots 0, 1, 3) ----
  for (int i = tid; i < 2160; i += 256) {
    int st = i / 720;
    int r  = i - st * 720;
    int j = r / 45, c4 = r - j * 45;
    long ro = (long)j * N_ + c4 * 4;
    long slot = (st == 2) ? 3 : st;     // l4->0, l23->1, adapt->3
    s16x4 h = *(const s16x4*)&stg[st][j*180 + c4*4];
    __builtin_nontemporal_store(bf4_to_f4(h), (f32x4*)(base + slot*BSN_ + ro));
  }
}

extern "C" void kernel_launch(void* const* d_in, const int* in_sizes, int n_in,
                              void* d_out, int out_size, void* d_ws, size_t ws_size,
                              hipStream_t stream) {
  const int*   ori    = (const int*)d_in[0];
  const float* logits = (const float*)d_in[1];
  const float* plog   = (const float*)d_in[2];
  const float* narrow = (const float*)d_in[3];
  const float* broad  = (const float*)d_in[4];
  float* out = (float*)d_out;

  float* ws    = (float*)d_ws;
  float* scale = ws;                  // BS_
  float* prec  = ws + BS_;            // BS_
  float* P     = ws + 2*BS_;          // CPN_
  float* tbnd  = P + CPN_;            // CPN_
  float* cp_a  = tbnd + CPN_;         // CPN_
  float* cp_l4 = cp_a + CPN_;         // CPN_
  short* cfrag = (short*)(cp_l4 + CPN_);

  k0_prep<<<144, 256, 0, stream>>>(narrow, broad, cfrag);
  k_cp<<<B_, 256, 0, stream>>>(ori, cp_a, cp_l4);
  k_a<<<dim3(16, B_), 256, 0, stream>>>(logits, plog, scale, prec, P);
  k_comb<<<360, 256, 0, stream>>>(P, tbnd);
  k_main<<<dim3(16, B_), 256, 0, stream>>>(ori, logits, scale, prec,
                                           cp_a, cp_l4, tbnd, cfrag, out);
}

// Round 15
// 158.051 us; speedup vs baseline: 1.1377x; 1.0665x over previous
//
#include <hip/hip_runtime.h>
#include <hip/hip_bf16.h>

#define B_ 512
#define S_ 256
#define N_ 180
#define BS_ (B_*S_)            // 131072
#define BSN_ ((long)BS_*N_)    // 23592960
#define CPN_ ((long)B_*16*N_)  // checkpoint elems
#define A16F 0.028147497671065603f   // 0.8^16

typedef __attribute__((ext_vector_type(4))) float f32x4;
typedef __attribute__((ext_vector_type(4))) short s16x4;
typedef __attribute__((ext_vector_type(8))) short s16x8;

static __device__ inline short f2bf(float f) {
  union { float f; unsigned u; } v; v.f = f;
  unsigned r = v.u + 0x7FFF + ((v.u >> 16) & 1);   // RNE
  return (short)(r >> 16);
}
static __device__ inline float bf2f(short h) {
  union { float f; unsigned u; } v; v.u = ((unsigned)(unsigned short)h) << 16;
  return v.f;
}
static __device__ inline f32x4 bf4_to_f4(s16x4 h) {
  f32x4 v; v.x = bf2f(h.x); v.y = bf2f(h.y); v.z = bf2f(h.z); v.w = bf2f(h.w);
  return v;
}
static __device__ inline void lds_barrier() {
  asm volatile("s_waitcnt lgkmcnt(0)" ::: "memory");
  __builtin_amdgcn_s_barrier();
}

// K_a: grid (17, B_).
//  x < 16 : per-(chunk x, batch b): scale/prec, chunk-local template partial P
//  x == 16: k_cp fold (l4/adapt checkpoints, reads only ori) + k0 fold (cfrag)
__global__ __launch_bounds__(256) void k_a(
    const float* __restrict__ logits, const float* __restrict__ plog,
    const int* __restrict__ ori, const float* __restrict__ narrow,
    const float* __restrict__ broad,
    float* __restrict__ scale, float* __restrict__ prec, float* __restrict__ P,
    float* __restrict__ cp_a, float* __restrict__ cp_l4,
    short* __restrict__ cfrag) {
  int x = blockIdx.x, b = blockIdx.y;
  int tid = threadIdx.x;

  if (x == 16) {
    // ---- k_cp: serial l4/adapt checkpoint scan ----
    __shared__ int o_l[256];
    o_l[tid] = ori[b*S_ + tid];
    __syncthreads();
    if (tid < N_) {
      int n = tid;
      float a = 0.f, l4 = 0.f;
      long cb = (long)b * 16 * N_ + n;
      for (int s = 0; s < S_; ++s) {
        if ((s & 15) == 0) {
          cp_a [cb + (s >> 4) * N_] = a;
          cp_l4[cb + (s >> 4) * N_] = l4;
        }
        a = 0.9f * a + 0.2f * l4;
        if (n == o_l[s]) {
          float d = fmaxf(1.f - a, 0.f);
          l4 = d * __builtin_amdgcn_rcpf(1.f + d * (1.f/180.f));
        } else l4 = 0.f;
      }
    }
    // ---- k0 fold: cfrag built by blocks b < 144 ----
    if (b < 144) {
      int idx = b * 256 + tid;
      if (idx < 12*6*64*8) {
        int j    = idx & 7;
        int lane = (idx >> 3) & 63;
        int g    = idx >> 9;
        int ks   = g % 6;
        int nt   = g / 6;
        int k = ks*32 + (lane >> 4)*8 + j;
        int c = nt*16 + (lane & 15);
        float v = 0.f;
        if (k < N_ && c < N_) v = broad[k*N_ + c] - 0.5f*narrow[k*N_ + c];
        cfrag[idx] = f2bf(v);
      }
    }
    return;
  }

  // ---- original k_a: chunk x, batch b ----
  __shared__ float u[16*180];
  int k = x;
  int w = tid >> 6, l = tid & 63;
  bool seg2 = (l < N_ - 128);
  int s0 = k * 16;
  const float* Lb = logits + ((long)b*S_ + s0) * N_;
  #pragma unroll
  for (int q = 0; q < 4; ++q) {
    int r = w*4 + q;
    const float* rp = Lb + (long)r * N_;
    float e0 = __expf(rp[l]);
    float e1 = __expf(rp[l + 64]);
    float e2 = seg2 ? __expf(rp[l + 128]) : 0.f;
    float s = e0 + e1 + e2;
    #pragma unroll
    for (int o = 32; o; o >>= 1) s += __shfl_xor(s, o);
    float pr = 1.f / (1.f + __expf(-plog[b*S_ + s0 + r]));
    float scv = 0.2f * pr / s;
    if (l == 0) { scale[b*S_ + s0 + r] = scv; prec[b*S_ + s0 + r] = pr; }
    u[r*180 + l] = e0 * scv;
    u[r*180 + l + 64] = e1 * scv;
    if (seg2) u[r*180 + l + 128] = e2 * scv;
  }
  __syncthreads();
  if (tid < N_) {
    float c = 0.f;
    #pragma unroll
    for (int r = 0; r < 16; ++r) c = 0.8f * c + u[r*180 + tid];
    P[((long)b*16 + k) * N_ + tid] = c;
  }
}

// K_comb: cross-chunk template prefix: t_bnd[k] = 0.8^16 * t_bnd[k-1] + P[k-1]
__global__ void k_comb(const float* __restrict__ P, float* __restrict__ tbnd) {
  int t = blockIdx.x * 256 + threadIdx.x;   // exactly 92160 = 512*180
  int b = t / N_, n = t - b * N_;
  long pb = (long)b * 16 * N_ + n;
  float c = 0.f;
  tbnd[pb] = 0.f;
  #pragma unroll
  for (int k = 1; k < 16; ++k) {
    c = A16F * c + P[pb + (k - 1) * N_];
    tbnd[pb + k * N_] = c;
  }
}

// K_main: one block per (batch, chunk). WARM warm rows recomputed from exact
// boundary state; l23 via 0.5-contraction warm-up. bf16 LDS staging
// (~42 KB -> 3 blk/CU); wave 3 streams template+comparator NT stores during
// the scan phase.
template<int WARM>
__global__ __launch_bounds__(256, 3) void k_main(
    const int* __restrict__ ori, const float* __restrict__ logits,
    const float* __restrict__ scale, const float* __restrict__ prec,
    const float* __restrict__ cp_a, const float* __restrict__ cp_l4,
    const float* __restrict__ tbnd, const short* __restrict__ cfrag,
    float* __restrict__ out) {
  constexpr int NROW = WARM + 16;
  constexpr int MT = NROW / 16;
  __shared__ short At[NROW * 200];      // template bf16, padded K (stride 200)
  __shared__ short cmpb[NROW * 180];    // comparator bf16
  __shared__ short stg[3][16 * 180];    // l4 / l23 / adapt, bf16
  __shared__ float sc_l[NROW], pr_l[NROW];
  __shared__ int o_l[NROW];

  int b = blockIdx.y;
  int c = WARM ? (blockIdx.x + 1) : 0;
  int s0 = c * 16 - WARM;
  int tid = threadIdx.x, w = tid >> 6, l = tid & 63, lr = l & 15, lg = l >> 4;
  bool act = (tid < N_);
  int n = tid;

  if (tid < NROW) {
    int s = s0 + tid;
    sc_l[tid] = scale[b*S_ + s];
    pr_l[tid] = prec[b*S_ + s];
    o_l[tid]  = ori[b*S_ + s];
  }
  for (int i = tid; i < NROW * 20; i += 256) {   // zero-pad At cols 180..199
    int r = i / 20, q = i - r * 20;
    At[r * 200 + 180 + q] = 0;
  }
  long bnd = WARM ? (((long)b*16 + (c - 1)) * N_ + n) : 0;
  float* base = out + ((long)b*S_ + c*16) * N_;
  lds_barrier();

  // ---- phase 1: template recursion from exact boundary (f32 logits) ----
  if (act) {
    float t = WARM ? tbnd[bnd] : 0.f;
    const float* lp = logits + ((long)b*S_ + s0) * N_ + n;
    for (int jc = 0; jc < NROW; jc += 8) {
      float xs[8];
      #pragma unroll
      for (int r = 0; r < 8; ++r) xs[r] = lp[(long)(jc + r) * N_];
      #pragma unroll
      for (int r = 0; r < 8; ++r) {
        t = 0.8f * t + __expf(xs[r]) * sc_l[jc + r];
        At[(jc + r) * 200 + n] = f2bf(t);
      }
    }
  }
  lds_barrier();

  // ---- phase 2: comparator GEMM (template @ C) * prec -> cmpb (bf16) ----
  for (int i = 0; i < 3; ++i) {
    int ntile = i * 4 + w;
    s16x8 bfv[6];
    #pragma unroll
    for (int ks = 0; ks < 6; ++ks)
      bfv[ks] = *(const s16x8*)(cfrag + ((ntile*6 + ks)*64 + l)*8);
    #pragma unroll
    for (int mt = 0; mt < MT; ++mt) {
      f32x4 acc = (f32x4)(0.f);
      #pragma unroll
      for (int ks = 0; ks < 6; ++ks) {
        s16x8 af = *(const s16x8*)(&At[(mt*16 + lr)*200 + ks*32 + lg*8]);
        acc = __builtin_amdgcn_mfma_f32_16x16x32_bf16(af, bfv[ks], acc, 0, 0, 0);
      }
      int col = ntile * 16 + lr;
      if (col < N_) {
        #pragma unroll
        for (int r = 0; r < 4; ++r) {
          int row = mt*16 + lg*4 + r;
          cmpb[row * 180 + col] = f2bf(acc[r] * pr_l[row]);
        }
      }
    }
  }
  lds_barrier();

  // ---- phase 3 (threads 0..179): l4/adapt/l23 -> stg (bf16)
  // ---- phase 4a (wave 3): stream template+comparator NT stores meanwhile
  if (act) {
    float a  = WARM ? cp_a [bnd] : 0.f;
    float l4 = WARM ? cp_l4[bnd] : 0.f;
    float cl = 0.f;
    for (int jc = 0; jc < NROW; jc += 8) {
      float tv[8], qv[8]; int ov[8];
      #pragma unroll
      for (int r = 0; r < 8; ++r) {
        tv[r] = bf2f(At[(jc + r) * 200 + n]);
        qv[r] = bf2f(cmpb[(jc + r) * 180 + n]);
        ov[r] = o_l[jc + r];
      }
      #pragma unroll
      for (int r = 0; r < 8; ++r) {
        int j = jc + r;
        a = 0.9f * a + 0.2f * l4;
        float d = (n == ov[r]) ? fmaxf(1.f - a, 0.f) : 0.f;
        l4 = d * __builtin_amdgcn_rcpf(1.f + d * (1.f/180.f));
        cl = fmaxf(l4 + 0.5f * cl + tv[r] - qv[r], 0.f);
        if (j >= WARM) {
          int jj = j - WARM;
          stg[0][jj*180 + n] = f2bf(l4);
          stg[1][jj*180 + n] = f2bf(cl);
          stg[2][jj*180 + n] = f2bf(a);
        }
      }
    }
  } else if (tid >= 192) {
    // wave 3: 1440 groups (2 streams x 16 rows x 45 f32x4)
    for (int g = tid - 192; g < 1440; g += 64) {
      int st = g / 720;
      int i  = g - st * 720;
      int j = i / 45, c4 = i - j * 45;
      long ro = (long)j * N_ + c4 * 4;
      if (st == 0) {
        s16x4 h = *(const s16x4*)&At[(WARM + j)*200 + c4*4];
        __builtin_nontemporal_store(bf4_to_f4(h), (f32x4*)(base + 2*BSN_ + ro));
      } else {
        s16x4 h = *(const s16x4*)&cmpb[(WARM + j)*180 + c4*4];
        __builtin_nontemporal_store(bf4_to_f4(h), (f32x4*)(base + 4*BSN_ + ro));
      }
    }
  }
  lds_barrier();

  // ---- phase 4b: l4/l23/adapt NT stores (slots 0, 1, 3) ----
  for (int i = tid; i < 2160; i += 256) {
    int st = i / 720;
    int r  = i - st * 720;
    int j = r / 45, c4 = r - j * 45;
    long ro = (long)j * N_ + c4 * 4;
    long slot = (st == 2) ? 3 : st;     // l4->0, l23->1, adapt->3
    s16x4 h = *(const s16x4*)&stg[st][j*180 + c4*4];
    __builtin_nontemporal_store(bf4_to_f4(h), (f32x4*)(base + slot*BSN_ + ro));
  }
}

extern "C" void kernel_launch(void* const* d_in, const int* in_sizes, int n_in,
                              void* d_out, int out_size, void* d_ws, size_t ws_size,
                              hipStream_t stream) {
  const int*   ori    = (const int*)d_in[0];
  const float* logits = (const float*)d_in[1];
  const float* plog   = (const float*)d_in[2];
  const float* narrow = (const float*)d_in[3];
  const float* broad  = (const float*)d_in[4];
  float* out = (float*)d_out;

  float* ws    = (float*)d_ws;
  float* scale = ws;                  // BS_
  float* prec  = ws + BS_;            // BS_
  float* P     = ws + 2*BS_;          // CPN_
  float* tbnd  = P + CPN_;            // CPN_
  float* cp_a  = tbnd + CPN_;         // CPN_
  float* cp_l4 = cp_a + CPN_;         // CPN_
  short* cfrag = (short*)(cp_l4 + CPN_);

  k_a<<<dim3(17, B_), 256, 0, stream>>>(logits, plog, ori, narrow, broad,
                                        scale, prec, P, cp_a, cp_l4, cfrag);
  k_comb<<<360, 256, 0, stream>>>(P, tbnd);
  k_main<0><<<dim3(1, B_), 256, 0, stream>>>(ori, logits, scale, prec,
                                             cp_a, cp_l4, tbnd, cfrag, out);
  k_main<16><<<dim3(15, B_), 256, 0, stream>>>(ori, logits, scale, prec,
                                               cp_a, cp_l4, tbnd, cfrag, out);
}

// Round 16
// 156.468 us; speedup vs baseline: 1.1492x; 1.0101x over previous
//
#include <hip/hip_runtime.h>
#include <hip/hip_bf16.h>

#define B_ 512
#define S_ 256
#define N_ 180
#define BS_ (B_*S_)            // 131072
#define BSN_ ((long)BS_*N_)    // 23592960
#define CPN_ ((long)B_*16*N_)  // checkpoint elems
#define A16F 0.028147497671065603f   // 0.8^16

typedef __attribute__((ext_vector_type(4))) float f32x4;
typedef __attribute__((ext_vector_type(4))) short s16x4;
typedef __attribute__((ext_vector_type(8))) short s16x8;

static __device__ inline short f2bf(float f) {
  union { float f; unsigned u; } v; v.f = f;
  unsigned r = v.u + 0x7FFF + ((v.u >> 16) & 1);   // RNE
  return (short)(r >> 16);
}
static __device__ inline float bf2f(short h) {
  union { float f; unsigned u; } v; v.u = ((unsigned)(unsigned short)h) << 16;
  return v.f;
}
static __device__ inline f32x4 bf4_to_f4(s16x4 h) {
  f32x4 v; v.x = bf2f(h.x); v.y = bf2f(h.y); v.z = bf2f(h.z); v.w = bf2f(h.w);
  return v;
}
static __device__ inline void lds_barrier() {
  asm volatile("s_waitcnt lgkmcnt(0)" ::: "memory");
  __builtin_amdgcn_s_barrier();
}

// K_a: grid (17, B_).
//  x < 16 : per-(chunk x, batch b): scale/prec, chunk-local template partial P
//  x == 16: k_cp fold (l4/adapt checkpoints, reads only ori) + k0 fold (cfrag)
__global__ __launch_bounds__(256) void k_a(
    const float* __restrict__ logits, const float* __restrict__ plog,
    const int* __restrict__ ori, const float* __restrict__ narrow,
    const float* __restrict__ broad,
    float* __restrict__ scale, float* __restrict__ prec, float* __restrict__ P,
    float* __restrict__ cp_a, float* __restrict__ cp_l4,
    short* __restrict__ cfrag) {
  int x = blockIdx.x, b = blockIdx.y;
  int tid = threadIdx.x;

  if (x == 16) {
    // ---- k_cp: serial l4/adapt checkpoint scan ----
    __shared__ int o_l[256];
    o_l[tid] = ori[b*S_ + tid];
    __syncthreads();
    if (tid < N_) {
      int n = tid;
      float a = 0.f, l4 = 0.f;
      long cb = (long)b * 16 * N_ + n;
      for (int s = 0; s < S_; ++s) {
        if ((s & 15) == 0) {
          cp_a [cb + (s >> 4) * N_] = a;
          cp_l4[cb + (s >> 4) * N_] = l4;
        }
        a = 0.9f * a + 0.2f * l4;
        if (n == o_l[s]) {
          float d = fmaxf(1.f - a, 0.f);
          l4 = d * __builtin_amdgcn_rcpf(1.f + d * (1.f/180.f));
        } else l4 = 0.f;
      }
    }
    // ---- k0 fold: cfrag built by blocks b < 144 ----
    if (b < 144) {
      int idx = b * 256 + tid;
      if (idx < 12*6*64*8) {
        int j    = idx & 7;
        int lane = (idx >> 3) & 63;
        int g    = idx >> 9;
        int ks   = g % 6;
        int nt   = g / 6;
        int k = ks*32 + (lane >> 4)*8 + j;
        int c = nt*16 + (lane & 15);
        float v = 0.f;
        if (k < N_ && c < N_) v = broad[k*N_ + c] - 0.5f*narrow[k*N_ + c];
        cfrag[idx] = f2bf(v);
      }
    }
    return;
  }

  // ---- original k_a: chunk x, batch b ----
  __shared__ float u[16*180];
  int k = x;
  int w = tid >> 6, l = tid & 63;
  bool seg2 = (l < N_ - 128);
  int s0 = k * 16;
  const float* Lb = logits + ((long)b*S_ + s0) * N_;
  #pragma unroll
  for (int q = 0; q < 4; ++q) {
    int r = w*4 + q;
    const float* rp = Lb + (long)r * N_;
    float e0 = __expf(rp[l]);
    float e1 = __expf(rp[l + 64]);
    float e2 = seg2 ? __expf(rp[l + 128]) : 0.f;
    float s = e0 + e1 + e2;
    #pragma unroll
    for (int o = 32; o; o >>= 1) s += __shfl_xor(s, o);
    float pr = 1.f / (1.f + __expf(-plog[b*S_ + s0 + r]));
    float scv = 0.2f * pr / s;
    if (l == 0) { scale[b*S_ + s0 + r] = scv; prec[b*S_ + s0 + r] = pr; }
    u[r*180 + l] = e0 * scv;
    u[r*180 + l + 64] = e1 * scv;
    if (seg2) u[r*180 + l + 128] = e2 * scv;
  }
  __syncthreads();
  if (tid < N_) {
    float c = 0.f;
    #pragma unroll
    for (int r = 0; r < 16; ++r) c = 0.8f * c + u[r*180 + tid];
    P[((long)b*16 + k) * N_ + tid] = c;
  }
}

// K_main: one block per (batch, chunk). WARM warm rows recomputed from exact
// boundary state; l23 via 0.5-contraction warm-up. bf16 LDS staging
// (~42 KB -> 3 blk/CU); wave 3 streams template+comparator NT stores during
// the scan phase. WARM==0 additionally computes tbnd (k_comb fold) for the
// whole batch before its own chunk-0 work.
template<int WARM>
__global__ __launch_bounds__(256, 3) void k_main(
    const int* __restrict__ ori, const float* __restrict__ logits,
    const float* __restrict__ scale, const float* __restrict__ prec,
    const float* __restrict__ cp_a, const float* __restrict__ cp_l4,
    const float* __restrict__ P, float* __restrict__ tbnd,
    const short* __restrict__ cfrag, float* __restrict__ out) {
  constexpr int NROW = WARM + 16;
  constexpr int MT = NROW / 16;
  __shared__ short At[NROW * 200];      // template bf16, padded K (stride 200)
  __shared__ short cmpb[NROW * 180];    // comparator bf16
  __shared__ short stg[3][16 * 180];    // l4 / l23 / adapt, bf16
  __shared__ float sc_l[NROW], pr_l[NROW];
  __shared__ int o_l[NROW];

  int b = blockIdx.y;
  int c = WARM ? (blockIdx.x + 1) : 0;
  int s0 = c * 16 - WARM;
  int tid = threadIdx.x, w = tid >> 6, l = tid & 63, lr = l & 15, lg = l >> 4;
  bool act = (tid < N_);
  int n = tid;

  if (tid < NROW) {
    int s = s0 + tid;
    sc_l[tid] = scale[b*S_ + s];
    pr_l[tid] = prec[b*S_ + s];
    o_l[tid]  = ori[b*S_ + s];
  }
  for (int i = tid; i < NROW * 20; i += 256) {   // zero-pad At cols 180..199
    int r = i / 20, q = i - r * 20;
    At[r * 200 + 180 + q] = 0;
  }
  long bnd = WARM ? (((long)b*16 + (c - 1)) * N_ + n) : 0;
  float* base = out + ((long)b*S_ + c*16) * N_;

  // ---- phase 0 (WARM==0 only): k_comb fold — batch tbnd prefix over P ----
  if constexpr (WARM == 0) {
    if (act) {
      long pb = (long)b * 16 * N_ + n;
      float t = 0.f;
      tbnd[pb] = 0.f;
      #pragma unroll
      for (int k = 1; k < 16; ++k) {
        t = A16F * t + P[pb + (k - 1) * N_];
        tbnd[pb + k * N_] = t;
      }
    }
  }
  lds_barrier();

  // ---- phase 1: template recursion from exact boundary (f32 logits) ----
  if (act) {
    float t = WARM ? tbnd[bnd] : 0.f;
    const float* lp = logits + ((long)b*S_ + s0) * N_ + n;
    for (int jc = 0; jc < NROW; jc += 8) {
      float xs[8];
      #pragma unroll
      for (int r = 0; r < 8; ++r) xs[r] = lp[(long)(jc + r) * N_];
      #pragma unroll
      for (int r = 0; r < 8; ++r) {
        t = 0.8f * t + __expf(xs[r]) * sc_l[jc + r];
        At[(jc + r) * 200 + n] = f2bf(t);
      }
    }
  }
  lds_barrier();

  // ---- phase 2: comparator GEMM (template @ C) * prec -> cmpb (bf16) ----
  for (int i = 0; i < 3; ++i) {
    int ntile = i * 4 + w;
    s16x8 bfv[6];
    #pragma unroll
    for (int ks = 0; ks < 6; ++ks)
      bfv[ks] = *(const s16x8*)(cfrag + ((ntile*6 + ks)*64 + l)*8);
    #pragma unroll
    for (int mt = 0; mt < MT; ++mt) {
      f32x4 acc = (f32x4)(0.f);
      #pragma unroll
      for (int ks = 0; ks < 6; ++ks) {
        s16x8 af = *(const s16x8*)(&At[(mt*16 + lr)*200 + ks*32 + lg*8]);
        acc = __builtin_amdgcn_mfma_f32_16x16x32_bf16(af, bfv[ks], acc, 0, 0, 0);
      }
      int col = ntile * 16 + lr;
      if (col < N_) {
        #pragma unroll
        for (int r = 0; r < 4; ++r) {
          int row = mt*16 + lg*4 + r;
          cmpb[row * 180 + col] = f2bf(acc[r] * pr_l[row]);
        }
      }
    }
  }
  lds_barrier();

  // ---- phase 3 (threads 0..179): l4/adapt/l23 -> stg (bf16)
  // ---- phase 4a (wave 3): stream template+comparator NT stores meanwhile
  if (act) {
    float a  = WARM ? cp_a [bnd] : 0.f;
    float l4 = WARM ? cp_l4[bnd] : 0.f;
    float cl = 0.f;
    for (int jc = 0; jc < NROW; jc += 8) {
      float tv[8], qv[8]; int ov[8];
      #pragma unroll
      for (int r = 0; r < 8; ++r) {
        tv[r] = bf2f(At[(jc + r) * 200 + n]);
        qv[r] = bf2f(cmpb[(jc + r) * 180 + n]);
        ov[r] = o_l[jc + r];
      }
      #pragma unroll
      for (int r = 0; r < 8; ++r) {
        int j = jc + r;
        a = 0.9f * a + 0.2f * l4;
        float d = (n == ov[r]) ? fmaxf(1.f - a, 0.f) : 0.f;
        l4 = d * __builtin_amdgcn_rcpf(1.f + d * (1.f/180.f));
        cl = fmaxf(l4 + 0.5f * cl + tv[r] - qv[r], 0.f);
        if (j >= WARM) {
          int jj = j - WARM;
          stg[0][jj*180 + n] = f2bf(l4);
          stg[1][jj*180 + n] = f2bf(cl);
          stg[2][jj*180 + n] = f2bf(a);
        }
      }
    }
  } else if (tid >= 192) {
    // wave 3: 1440 groups (2 streams x 16 rows x 45 f32x4)
    for (int g = tid - 192; g < 1440; g += 64) {
      int st = g / 720;
      int i  = g - st * 720;
      int j = i / 45, c4 = i - j * 45;
      long ro = (long)j * N_ + c4 * 4;
      if (st == 0) {
        s16x4 h = *(const s16x4*)&At[(WARM + j)*200 + c4*4];
        __builtin_nontemporal_store(bf4_to_f4(h), (f32x4*)(base + 2*BSN_ + ro));
      } else {
        s16x4 h = *(const s16x4*)&cmpb[(WARM + j)*180 + c4*4];
        __builtin_nontemporal_store(bf4_to_f4(h), (f32x4*)(base + 4*BSN_ + ro));
      }
    }
  }
  lds_barrier();

  // ---- phase 4b: l4/l23/adapt NT stores (slots 0, 1, 3) ----
  for (int i = tid; i < 2160; i += 256) {
    int st = i / 720;
    int r  = i - st * 720;
    int j = r / 45, c4 = r - j * 45;
    long ro = (long)j * N_ + c4 * 4;
    long slot = (st == 2) ? 3 : st;     // l4->0, l23->1, adapt->3
    s16x4 h = *(const s16x4*)&stg[st][j*180 + c4*4];
    __builtin_nontemporal_store(bf4_to_f4(h), (f32x4*)(base + slot*BSN_ + ro));
  }
}

extern "C" void kernel_launch(void* const* d_in, const int* in_sizes, int n_in,
                              void* d_out, int out_size, void* d_ws, size_t ws_size,
                              hipStream_t stream) {
  const int*   ori    = (const int*)d_in[0];
  const float* logits = (const float*)d_in[1];
  const float* plog   = (const float*)d_in[2];
  const float* narrow = (const float*)d_in[3];
  const float* broad  = (const float*)d_in[4];
  float* out = (float*)d_out;

  float* ws    = (float*)d_ws;
  float* scale = ws;                  // BS_
  float* prec  = ws + BS_;            // BS_
  float* P     = ws + 2*BS_;          // CPN_
  float* tbnd  = P + CPN_;            // CPN_
  float* cp_a  = tbnd + CPN_;         // CPN_
  float* cp_l4 = cp_a + CPN_;         // CPN_
  short* cfrag = (short*)(cp_l4 + CPN_);

  k_a<<<dim3(17, B_), 256, 0, stream>>>(logits, plog, ori, narrow, broad,
                                        scale, prec, P, cp_a, cp_l4, cfrag);
  k_main<0><<<dim3(1, B_), 256, 0, stream>>>(ori, logits, scale, prec,
                                             cp_a, cp_l4, P, tbnd, cfrag, out);
  k_main<16><<<dim3(15, B_), 256, 0, stream>>>(ori, logits, scale, prec,
                                               cp_a, cp_l4, P, tbnd, cfrag, out);
}